// Round 5
// baseline (450.662 us; speedup 1.0000x reference)
//
#include <hip/hip_runtime.h>
#include <math.h>

#define NEG_SLOPE 0.2f
#define GAT_EPS 1e-16f
#define LOG2E 1.44269504088896340736f

// ---- bf16 pair packing helpers (channel 2p in low half, 2p+1 in high) ----
__device__ __forceinline__ unsigned pack_bf16(float a, float b) {
    unsigned ua = __float_as_uint(a);
    unsigned ub = __float_as_uint(b);
    ua = (ua + 0x8000u) >> 16;
    ub = (ub + 0x8000u) & 0xffff0000u;
    return ua | ub;
}
__device__ __forceinline__ float bf_lo(unsigned pk) {
    return __uint_as_float(pk << 16);
}
__device__ __forceinline__ float bf_hi(unsigned pk) {
    return __uint_as_float(pk & 0xffff0000u);
}

// ===========================================================================
// CSR build, direct atomic form (within-row order is non-deterministic, but
// so was the old LDS-cursor sort; fp32 reorder noise ~1e-6 << bf16 payload
// error 8e-3). deg[] histogram is fused into k_gemm1 (global atomics hidden
// under the GEMM). Self-loops contribute +1 per node, folded in at scan1.
//   scan1: per-256-node block exscan of (deg+1) -> row_ptr (local), bsum
//   scan2: 1-block exscan of bsum -> bases; row_ptr[N] = Etot
//   fix:   row_ptr[d] += bases[blk]; cur[d] = row_ptr[d]
//   scatter: pos = atomicAdd(cur[dst]); csr_src[pos] = src
// ===========================================================================

__global__ __launch_bounds__(256) void k_scan1(
    const int* __restrict__ deg, int* __restrict__ row_ptr,
    int* __restrict__ bsum, int N)
{
    __shared__ int sm[256];
    int t = threadIdx.x;
    int d = blockIdx.x * 256 + t;
    int v = (d < N) ? deg[d] + 1 : 0;   // +1 = self-loop
    sm[t] = v;
    __syncthreads();
    for (int o = 1; o < 256; o <<= 1) {
        int u = (t >= o) ? sm[t - o] : 0;
        __syncthreads();
        sm[t] += u;
        __syncthreads();
    }
    if (d < N) row_ptr[d] = sm[t] - v;   // block-local exclusive
    if (t == 255) bsum[blockIdx.x] = sm[255];
}

__global__ __launch_bounds__(512) void k_scan2(
    const int* __restrict__ bsum, int* __restrict__ bases, int NB,
    int* __restrict__ row_ptr, int N, int Etot)
{
    __shared__ int sm[512];
    int t = threadIdx.x;
    int v = (t < NB) ? bsum[t] : 0;
    sm[t] = v;
    __syncthreads();
    for (int o = 1; o < 512; o <<= 1) {
        int u = (t >= o) ? sm[t - o] : 0;
        __syncthreads();
        sm[t] += u;
        __syncthreads();
    }
    if (t < NB) bases[t] = sm[t] - v;
    if (t == 0) row_ptr[N] = Etot;
}

__global__ __launch_bounds__(256) void k_fix(
    const int* __restrict__ bases, int* __restrict__ row_ptr,
    int* __restrict__ cur, int N)
{
    int d = blockIdx.x * 256 + threadIdx.x;
    if (d < N) {
        int r = bases[blockIdx.x] + row_ptr[d];
        row_ptr[d] = r;
        cur[d] = r;
    }
}

__global__ __launch_bounds__(256) void k_scatter(
    const int* __restrict__ ei, int E, int N,
    int* __restrict__ cur, int* __restrict__ csr_src)
{
    int Etot = E + N;
    int stride = gridDim.x * 256;
    for (int e = blockIdx.x * 256 + threadIdx.x; e < Etot; e += stride) {
        int s, d;
        if (e < E) { s = ei[e]; d = ei[E + e]; }
        else       { s = e - E; d = s; }
        int pos = atomicAdd(&cur[d], 1);
        csr_src[pos] = s;
    }
}

// ===========================================================================
// xl1 = x @ W1 [N,64] -> packed bf16; as1/ad1 logits (pre-scaled by log2e).
// REGISTER-BLOCKED: each thread computes 4 NODES x 16 CHANNELS (64 acc) —
// each LDS w-read feeds 4 FMAs. Block covers 256 nodes. Also runs the
// degree histogram (global atomics, L2-resident, hidden under the GEMM).
// ===========================================================================
__device__ __forceinline__ void emit_node1(
    const float* acc, int n, int q, int c0,
    const float* asrc, const float* adst,
    unsigned* __restrict__ xl1b, float* __restrict__ as1,
    float* __restrict__ ad1)
{
    uint4 pk0, pk1;
    pk0.x = pack_bf16(acc[0], acc[1]);  pk0.y = pack_bf16(acc[2], acc[3]);
    pk0.z = pack_bf16(acc[4], acc[5]);  pk0.w = pack_bf16(acc[6], acc[7]);
    pk1.x = pack_bf16(acc[8], acc[9]);  pk1.y = pack_bf16(acc[10], acc[11]);
    pk1.z = pack_bf16(acc[12], acc[13]); pk1.w = pack_bf16(acc[14], acc[15]);
    uint4* xo = (uint4*)(xl1b + (size_t)n * 32 + q * 8);
    xo[0] = pk0;
    xo[1] = pk1;
#pragma unroll
    for (int hh = 0; hh < 2; hh++) {
        float s = 0.0f, t = 0.0f;
#pragma unroll
        for (int c = 0; c < 8; c++) {
            s = fmaf(acc[hh * 8 + c], asrc[c0 + hh * 8 + c], s);
            t = fmaf(acc[hh * 8 + c], adst[c0 + hh * 8 + c], t);
        }
        as1[(size_t)n * 8 + 2 * q + hh] = s * LOG2E;
        ad1[(size_t)n * 8 + 2 * q + hh] = t * LOG2E;
    }
}

__global__ __launch_bounds__(256) void k_gemm1(
    const float* __restrict__ x, const float* __restrict__ W1,
    const float* __restrict__ a_src1, const float* __restrict__ a_dst1,
    unsigned* __restrict__ xl1b, float* __restrict__ as1,
    float* __restrict__ ad1, int N, int F,
    const int* __restrict__ ei, int E, int* __restrict__ deg)
{
    __shared__ float Ws[128 * 64];
    __shared__ float asrc[64];
    __shared__ float adst[64];

    // ---- fused degree histogram (dst half of ei only; no sync needed) ----
    {
        int per = (E + (int)gridDim.x - 1) / (int)gridDim.x;
        int base = blockIdx.x * per;
        int lim = min(base + per, E);
        for (int e = base + threadIdx.x; e < lim; e += 256)
            atomicAdd(&deg[ei[E + e]], 1);
    }

    // ---- GEMM part ----
    for (int i = threadIdx.x; i < F * 64; i += 256) Ws[i] = W1[i];
    if (threadIdx.x < 64) {
        asrc[threadIdx.x] = a_src1[threadIdx.x];
        adst[threadIdx.x] = a_dst1[threadIdx.x];
    }
    __syncthreads();

    int q = threadIdx.x & 3;              // channel quarter: 16q..16q+15
    int n0 = blockIdx.x * 256 + (threadIdx.x >> 2) * 4;  // 4 consecutive nodes
    if (n0 >= N) return;
    int c0 = q * 16;
    int n1 = min(n0 + 1, N - 1);
    int n2 = min(n0 + 2, N - 1);
    int n3 = min(n0 + 3, N - 1);

    float acc0[16], acc1[16], acc2[16], acc3[16];
#pragma unroll
    for (int c = 0; c < 16; c++) { acc0[c]=0.f; acc1[c]=0.f; acc2[c]=0.f; acc3[c]=0.f; }

    const float4* xr0 = (const float4*)(x + (size_t)n0 * F);
    const float4* xr1 = (const float4*)(x + (size_t)n1 * F);
    const float4* xr2 = (const float4*)(x + (size_t)n2 * F);
    const float4* xr3 = (const float4*)(x + (size_t)n3 * F);

#define GEMM1_ROW(comp, ridx)                                        \
    { const float* w = &Ws[(k4 * 4 + ridx) * 64 + c0];               \
      _Pragma("unroll")                                              \
      for (int c = 0; c < 16; c++) {                                 \
          float wc = w[c];                                           \
          acc0[c] = fmaf(xv0.comp, wc, acc0[c]);                     \
          acc1[c] = fmaf(xv1.comp, wc, acc1[c]);                     \
          acc2[c] = fmaf(xv2.comp, wc, acc2[c]);                     \
          acc3[c] = fmaf(xv3.comp, wc, acc3[c]); } }

    for (int k4 = 0; k4 < F / 4; k4++) {
        float4 xv0 = xr0[k4];
        float4 xv1 = xr1[k4];
        float4 xv2 = xr2[k4];
        float4 xv3 = xr3[k4];
        GEMM1_ROW(x, 0)
        GEMM1_ROW(y, 1)
        GEMM1_ROW(z, 2)
        GEMM1_ROW(w, 3)
    }
#undef GEMM1_ROW

    emit_node1(acc0, n0, q, c0, asrc, adst, xl1b, as1, ad1);
    if (n0 + 1 < N) emit_node1(acc1, n0 + 1, q, c0, asrc, adst, xl1b, as1, ad1);
    if (n0 + 2 < N) emit_node1(acc2, n0 + 2, q, c0, asrc, adst, xl1b, as1, ad1);
    if (n0 + 3 < N) emit_node1(acc3, n0 + 3, q, c0, asrc, adst, xl1b, as1, ad1);
}

// ===========================================================================
// Layer-1 aggregation (pull): TWO DST NODES PER WAVE (32 lanes each:
// 4 edge groups x 8 channel lanes), edge loop unrolled x2. UNCHANGED —
// measured at the random-gather memory ceiling (3.57 TB/s, VALU 40%).
// ===========================================================================
__global__ __launch_bounds__(256) void k_agg1(
    const int* __restrict__ row_ptr, const int* __restrict__ csr_src,
    const float* __restrict__ as1, const float* __restrict__ ad1,
    const unsigned* __restrict__ xl1b, const float* __restrict__ b1,
    float* __restrict__ h1, int N)
{
    int d = blockIdx.x * 8 + ((threadIdx.x >> 6) << 1) + ((threadIdx.x >> 5) & 1);
    if (d >= N) return;
    int lane = threadIdx.x & 31;   // lane within this dst's half-wave
    int g = lane >> 3;   // edge group 0..3
    int l = lane & 7;    // head / channel octet

    int beg = row_ptr[d], end = row_ptr[d + 1];
    float adh = ad1[(size_t)d * 8 + l];

    float ax[8];
#pragma unroll
    for (int j = 0; j < 8; j++) ax[j] = 0.f;
    float den = 0.f;

    int i = beg + g;
    for (; i + 4 < end; i += 8) {
        int s0 = csr_src[i];
        int s1 = csr_src[i + 4];
        size_t q0 = (size_t)s0 * 8 + l;   // as1 index; payload = 4*q0
        size_t q1 = (size_t)s1 * 8 + l;
        float al0 = as1[q0] + adh;
        float al1 = as1[q1] + adh;
        uint4 k0 = *(const uint4*)(xl1b + (q0 << 2));
        uint4 k1 = *(const uint4*)(xl1b + (q1 << 2));
        al0 = fmaxf(al0, NEG_SLOPE * al0);
        al1 = fmaxf(al1, NEG_SLOPE * al1);
        float e0 = __builtin_amdgcn_exp2f(al0);
        float e1 = __builtin_amdgcn_exp2f(al1);
        ax[0] = fmaf(e0, bf_lo(k0.x), ax[0]);
        ax[1] = fmaf(e0, bf_hi(k0.x), ax[1]);
        ax[2] = fmaf(e0, bf_lo(k0.y), ax[2]);
        ax[3] = fmaf(e0, bf_hi(k0.y), ax[3]);
        ax[4] = fmaf(e0, bf_lo(k0.z), ax[4]);
        ax[5] = fmaf(e0, bf_hi(k0.z), ax[5]);
        ax[6] = fmaf(e0, bf_lo(k0.w), ax[6]);
        ax[7] = fmaf(e0, bf_hi(k0.w), ax[7]);
        ax[0] = fmaf(e1, bf_lo(k1.x), ax[0]);
        ax[1] = fmaf(e1, bf_hi(k1.x), ax[1]);
        ax[2] = fmaf(e1, bf_lo(k1.y), ax[2]);
        ax[3] = fmaf(e1, bf_hi(k1.y), ax[3]);
        ax[4] = fmaf(e1, bf_lo(k1.z), ax[4]);
        ax[5] = fmaf(e1, bf_hi(k1.z), ax[5]);
        ax[6] = fmaf(e1, bf_lo(k1.w), ax[6]);
        ax[7] = fmaf(e1, bf_hi(k1.w), ax[7]);
        den += e0 + e1;
    }
    if (i < end) {
        int s0 = csr_src[i];
        size_t q0 = (size_t)s0 * 8 + l;
        float al0 = as1[q0] + adh;
        uint4 k0 = *(const uint4*)(xl1b + (q0 << 2));
        al0 = fmaxf(al0, NEG_SLOPE * al0);
        float e0 = __builtin_amdgcn_exp2f(al0);
        ax[0] = fmaf(e0, bf_lo(k0.x), ax[0]);
        ax[1] = fmaf(e0, bf_hi(k0.x), ax[1]);
        ax[2] = fmaf(e0, bf_lo(k0.y), ax[2]);
        ax[3] = fmaf(e0, bf_hi(k0.y), ax[3]);
        ax[4] = fmaf(e0, bf_lo(k0.z), ax[4]);
        ax[5] = fmaf(e0, bf_hi(k0.z), ax[5]);
        ax[6] = fmaf(e0, bf_lo(k0.w), ax[6]);
        ax[7] = fmaf(e0, bf_hi(k0.w), ax[7]);
        den += e0;
    }

    // Reduce over the 4 edge groups: masks 8,16 stay inside each 32-lane half.
#pragma unroll
    for (int m = 8; m < 32; m <<= 1) {
#pragma unroll
        for (int j = 0; j < 8; j++) ax[j] += __shfl_xor(ax[j], m);
        den += __shfl_xor(den, m);
    }

    if (g == 0) {
        float inv = __builtin_amdgcn_rcpf(den + GAT_EPS);
        const float4* bb = (const float4*)(b1 + l * 8);
        float4 b0 = bb[0], b1v = bb[1];
        float4 o0, o1;
        float v;
        v = fmaf(ax[0], inv, b0.x);  o0.x = v > 0.f ? v : __expf(v) - 1.f;
        v = fmaf(ax[1], inv, b0.y);  o0.y = v > 0.f ? v : __expf(v) - 1.f;
        v = fmaf(ax[2], inv, b0.z);  o0.z = v > 0.f ? v : __expf(v) - 1.f;
        v = fmaf(ax[3], inv, b0.w);  o0.w = v > 0.f ? v : __expf(v) - 1.f;
        v = fmaf(ax[4], inv, b1v.x); o1.x = v > 0.f ? v : __expf(v) - 1.f;
        v = fmaf(ax[5], inv, b1v.y); o1.y = v > 0.f ? v : __expf(v) - 1.f;
        v = fmaf(ax[6], inv, b1v.z); o1.z = v > 0.f ? v : __expf(v) - 1.f;
        v = fmaf(ax[7], inv, b1v.w); o1.w = v > 0.f ? v : __expf(v) - 1.f;
        float4* op = (float4*)(h1 + (size_t)d * 64 + l * 8);
        op[0] = o0;
        op[1] = o1;
    }
}

// ===========================================================================
// Layer-2 node transform: REGISTER-BLOCKED — each thread computes 2 NODES x
// 20 CHANNELS (40 acc); each LDS w-read feeds 2 FMAs. Block covers 256
// nodes. Rows stride 24 uints (96 B): 20 payload + embedded as2 at uint 20.
// ===========================================================================
__global__ __launch_bounds__(256) void k_node2(
    const float* __restrict__ h1, const float* __restrict__ W2,
    const float* __restrict__ a_src2, const float* __restrict__ a_dst2,
    unsigned* __restrict__ xl2b, float* __restrict__ ad2, int N)
{
    __shared__ float Ws[64 * 40];
    __shared__ float a2s[40];
    __shared__ float a2d[40];
    for (int i = threadIdx.x; i < 64 * 40; i += 256) Ws[i] = W2[i];
    if (threadIdx.x < 40) {
        a2s[threadIdx.x] = a_src2[threadIdx.x];
        a2d[threadIdx.x] = a_dst2[threadIdx.x];
    }
    __syncthreads();

    int q = threadIdx.x & 1;              // channel half: 20q..20q+19
    int n0 = blockIdx.x * 256 + (threadIdx.x >> 1) * 2;  // 2 consecutive nodes
    if (n0 >= N) return;
    int c0 = q * 20;
    int n1 = min(n0 + 1, N - 1);

    float o0[20], o1[20];
#pragma unroll
    for (int j = 0; j < 20; j++) { o0[j] = 0.f; o1[j] = 0.f; }

    const float4* hr0 = (const float4*)(h1 + (size_t)n0 * 64);
    const float4* hr1 = (const float4*)(h1 + (size_t)n1 * 64);

#define NODE2_ROW(comp, ridx)                                        \
    { const float* w = &Ws[(k4 * 4 + ridx) * 40 + c0];               \
      _Pragma("unroll")                                              \
      for (int j = 0; j < 20; j++) {                                 \
          float wj = w[j];                                           \
          o0[j] = fmaf(ha.comp, wj, o0[j]);                          \
          o1[j] = fmaf(hb.comp, wj, o1[j]); } }

    for (int k4 = 0; k4 < 16; k4++) {
        float4 ha = hr0[k4];
        float4 hb = hr1[k4];
        NODE2_ROW(x, 0)
        NODE2_ROW(y, 1)
        NODE2_ROW(z, 2)
        NODE2_ROW(w, 3)
    }
#undef NODE2_ROW

    float s0 = 0.f, t0 = 0.f, s1 = 0.f, t1 = 0.f;
#pragma unroll
    for (int j = 0; j < 20; j++) {
        s0 = fmaf(o0[j], a2s[c0 + j], s0);
        t0 = fmaf(o0[j], a2d[c0 + j], t0);
        s1 = fmaf(o1[j], a2s[c0 + j], s1);
        t1 = fmaf(o1[j], a2d[c0 + j], t1);
    }
    s0 += __shfl_xor(s0, 1);
    t0 += __shfl_xor(t0, 1);
    s1 += __shfl_xor(s1, 1);
    t1 += __shfl_xor(t1, 1);
    if (q == 0) {
        xl2b[(size_t)n0 * 24 + 20] = __float_as_uint(s0 * LOG2E);
        ad2[n0] = t0 * LOG2E;
        if (n0 + 1 < N) {
            xl2b[(size_t)(n0 + 1) * 24 + 20] = __float_as_uint(s1 * LOG2E);
            ad2[n0 + 1] = t1 * LOG2E;
        }
    }

    unsigned* xo0 = xl2b + (size_t)n0 * 24 + q * 10;
#pragma unroll
    for (int p = 0; p < 10; p++) xo0[p] = pack_bf16(o0[2 * p], o0[2 * p + 1]);
    if (n0 + 1 < N) {
        unsigned* xo1 = xl2b + (size_t)(n0 + 1) * 24 + q * 10;
#pragma unroll
        for (int p = 0; p < 10; p++) xo1[p] = pack_bf16(o1[2 * p], o1[2 * p + 1]);
    }
}

// ===========================================================================
// Layer-2 aggregation (pull): TWO DST NODES PER WAVE. Rows stride 24:
// lane l<5 loads uint4 payload at +4l; the as2 logit is row[20] (same line
// as lane 4's quad). Lanes l>=5 fully predicated off.
// ===========================================================================
__global__ __launch_bounds__(256) void k_agg2(
    const int* __restrict__ row_ptr, const int* __restrict__ csr_src,
    const float* __restrict__ ad2,
    const unsigned* __restrict__ xl2b, const float* __restrict__ b2,
    float* __restrict__ out, int N)
{
    int d = blockIdx.x * 8 + ((threadIdx.x >> 6) << 1) + ((threadIdx.x >> 5) & 1);
    if (d >= N) return;
    int lane = threadIdx.x & 31;
    int g = lane >> 3;   // edge group 0..3
    int l = lane & 7;
    if (l >= 5) return;  // only 5 octets of 40 channels; reduction is l-local

    int beg = row_ptr[d], end = row_ptr[d + 1];
    float add = ad2[d];

    float ax[8];
#pragma unroll
    for (int j = 0; j < 8; j++) ax[j] = 0.f;
    float den = 0.f;

    int i = beg + g;
    for (; i + 4 < end; i += 8) {
        int s0 = csr_src[i];
        int s1 = csr_src[i + 4];
        const unsigned* r0 = xl2b + (size_t)s0 * 24;
        const unsigned* r1 = xl2b + (size_t)s1 * 24;
        float al0 = __uint_as_float(r0[20]) + add;
        float al1 = __uint_as_float(r1[20]) + add;
        uint4 k0 = *(const uint4*)(r0 + l * 4);
        uint4 k1 = *(const uint4*)(r1 + l * 4);
        al0 = fmaxf(al0, NEG_SLOPE * al0);
        al1 = fmaxf(al1, NEG_SLOPE * al1);
        float e0 = __builtin_amdgcn_exp2f(al0);
        float e1 = __builtin_amdgcn_exp2f(al1);
        ax[0] = fmaf(e0, bf_lo(k0.x), ax[0]);
        ax[1] = fmaf(e0, bf_hi(k0.x), ax[1]);
        ax[2] = fmaf(e0, bf_lo(k0.y), ax[2]);
        ax[3] = fmaf(e0, bf_hi(k0.y), ax[3]);
        ax[4] = fmaf(e0, bf_lo(k0.z), ax[4]);
        ax[5] = fmaf(e0, bf_hi(k0.z), ax[5]);
        ax[6] = fmaf(e0, bf_lo(k0.w), ax[6]);
        ax[7] = fmaf(e0, bf_hi(k0.w), ax[7]);
        ax[0] = fmaf(e1, bf_lo(k1.x), ax[0]);
        ax[1] = fmaf(e1, bf_hi(k1.x), ax[1]);
        ax[2] = fmaf(e1, bf_lo(k1.y), ax[2]);
        ax[3] = fmaf(e1, bf_hi(k1.y), ax[3]);
        ax[4] = fmaf(e1, bf_lo(k1.z), ax[4]);
        ax[5] = fmaf(e1, bf_hi(k1.z), ax[5]);
        ax[6] = fmaf(e1, bf_lo(k1.w), ax[6]);
        ax[7] = fmaf(e1, bf_hi(k1.w), ax[7]);
        den += e0 + e1;
    }
    if (i < end) {
        int s0 = csr_src[i];
        const unsigned* r0 = xl2b + (size_t)s0 * 24;
        float al0 = __uint_as_float(r0[20]) + add;
        uint4 k0 = *(const uint4*)(r0 + l * 4);
        al0 = fmaxf(al0, NEG_SLOPE * al0);
        float e0 = __builtin_amdgcn_exp2f(al0);
        ax[0] = fmaf(e0, bf_lo(k0.x), ax[0]);
        ax[1] = fmaf(e0, bf_hi(k0.x), ax[1]);
        ax[2] = fmaf(e0, bf_lo(k0.y), ax[2]);
        ax[3] = fmaf(e0, bf_hi(k0.y), ax[3]);
        ax[4] = fmaf(e0, bf_lo(k0.z), ax[4]);
        ax[5] = fmaf(e0, bf_hi(k0.z), ax[5]);
        ax[6] = fmaf(e0, bf_lo(k0.w), ax[6]);
        ax[7] = fmaf(e0, bf_hi(k0.w), ax[7]);
        den += e0;
    }

#pragma unroll
    for (int m = 8; m < 32; m <<= 1) {
#pragma unroll
        for (int j = 0; j < 8; j++) ax[j] += __shfl_xor(ax[j], m);
        den += __shfl_xor(den, m);
    }

    if (g == 0) {
        float inv = __builtin_amdgcn_rcpf(den + GAT_EPS);
        float* op = out + (size_t)d * 40 + l * 8;
        const float* bb = b2 + l * 8;
#pragma unroll
        for (int j = 0; j < 8; j++) op[j] = fmaf(ax[j], inv, bb[j]);
    }
}

extern "C" void kernel_launch(void* const* d_in, const int* in_sizes, int n_in,
                              void* d_out, int out_size, void* d_ws, size_t ws_size,
                              hipStream_t stream) {
    const float* x      = (const float*)d_in[0];
    const int*   ei     = (const int*)d_in[1];     // int32 on device
    const float* W1     = (const float*)d_in[2];
    const float* a_src1 = (const float*)d_in[3];
    const float* a_dst1 = (const float*)d_in[4];
    const float* b1     = (const float*)d_in[5];
    const float* W2     = (const float*)d_in[6];
    const float* a_src2 = (const float*)d_in[7];
    const float* a_dst2 = (const float*)d_in[8];
    const float* b2     = (const float*)d_in[9];

    int F = in_sizes[2] / 64;      // 128
    int N = in_sizes[0] / F;       // 100000
    int E = in_sizes[1] / 2;       // 1600000
    int Etot = E + N;
    int NB = (N + 255) / 256;      // 391 node blocks (NB <= 512 for N <= 131072)

    // Workspace (4-byte words).
    unsigned* xl1b    = (unsigned*)d_ws;                   // N*32
    float*    h1      = (float*)(xl1b + (size_t)N * 32);   // N*64
    float*    as1     = h1 + (size_t)N * 64;               // N*8
    float*    ad1     = as1 + (size_t)N * 8;               // N*8
    int*      row_ptr = (int*)(ad1 + (size_t)N * 8);       // N+1
    int*      csr_src = row_ptr + (N + 1);                 // Etot
    int*      deg     = csr_src + Etot;                    // N
    int*      cur     = deg + N;                           // N
    int*      bsum    = cur + N;                           // NB
    int*      bases   = bsum + NB;                         // NB
    // Layer-2 aliases (live only after k_agg1; originals dead by then):
    unsigned* xl2b    = xl1b;                              // N*24 rows (96 B)
    float*    ad2     = ad1;                               // N

    // ---- zero degree counters (stream-ordered, graph-capturable) ----
    hipMemsetAsync(deg, 0, (size_t)N * sizeof(int), stream);

    // ---- Layer-1 GEMM (256 nodes/block) + fused degree histogram ----
    k_gemm1<<<NB, 256, 0, stream>>>(x, W1, a_src1, a_dst1,
                                    xl1b, as1, ad1, N, F, ei, E, deg);

    // ---- CSR build: scan + atomic scatter (tiny kernels, high TLP) ----
    k_scan1<<<NB, 256, 0, stream>>>(deg, row_ptr, bsum, N);
    k_scan2<<<1, 512, 0, stream>>>(bsum, bases, NB, row_ptr, N, Etot);
    k_fix  <<<NB, 256, 0, stream>>>(bases, row_ptr, cur, N);
    {
        int gs = (Etot + 255) / 256;
        if (gs > 2048) gs = 2048;
        k_scatter<<<gs, 256, 0, stream>>>(ei, E, N, cur, csr_src);
    }

    // ---- Layer 1 aggregation ----
    k_agg1 <<<(N + 7) / 8, 256, 0, stream>>>(row_ptr, csr_src, as1, ad1,
                                             xl1b, b1, h1, N);

    // ---- Layer 2 ----
    k_node2<<<NB, 256, 0, stream>>>(h1, W2, a_src2, a_dst2, xl2b, ad2, N);
    k_agg2 <<<(N + 7) / 8, 256, 0, stream>>>(row_ptr, csr_src, ad2,
                                             xl2b, b2, (float*)d_out, N);
}

// Round 6
// 291.485 us; speedup vs baseline: 1.5461x; 1.5461x over previous
//
#include <hip/hip_runtime.h>
#include <math.h>

#define NEG_SLOPE 0.2f
#define GAT_EPS 1e-16f
#define LOG2E 1.44269504088896340736f

#define CH   2048   // edges per chunk (831 blocks -> TLP for latency)
#define NBK  512    // fine buckets; bucket = d >> SHIFT (256 nodes/bucket at shift=8)
// Pack constraint: s < 2^17 (N <= 131072) and (d & mask) in bits 17..17+shift.

// ---- bf16 pair packing helpers (channel 2p in low half, 2p+1 in high) ----
__device__ __forceinline__ unsigned pack_bf16(float a, float b) {
    unsigned ua = __float_as_uint(a);
    unsigned ub = __float_as_uint(b);
    ua = (ua + 0x8000u) >> 16;
    ub = (ub + 0x8000u) & 0xffff0000u;
    return ua | ub;
}
__device__ __forceinline__ float bf_lo(unsigned pk) {
    return __uint_as_float(pk << 16);
}
__device__ __forceinline__ float bf_hi(unsigned pk) {
    return __uint_as_float(pk & 0xffff0000u);
}

// ===========================================================================
// CSR build via deterministic two-level counting sort — ZERO global atomics.
// (Round-5 lesson: direct atomic scatter = 109 MB of dirty-line writes and
// 145 µs; the bucketed sort keeps csr_src writes window-local. Keep it.)
// Passes: cnt (fused into k_gemm1) -> off_a (parallel scan) -> place -> csr2.
// ===========================================================================

// Pass B: PARALLEL per-bucket exclusive scan over chunks (block = bucket).
__global__ __launch_bounds__(256) void k_off_a(
    const int* __restrict__ cnt, int* __restrict__ off,
    int* __restrict__ tot, int NCHv)
{
    __shared__ int sm[256];
    int b = blockIdx.x;
    int t = threadIdx.x;
    int carry = 0;
    for (int c0 = 0; c0 < NCHv; c0 += 256) {
        int c = c0 + t;
        int v = (c < NCHv) ? cnt[c * NBK + b] : 0;
        sm[t] = v;
        __syncthreads();
        for (int o = 1; o < 256; o <<= 1) {
            int add = (t >= o) ? sm[t - o] : 0;
            __syncthreads();
            sm[t] += add;
            __syncthreads();
        }
        if (c < NCHv) off[c * NBK + b] = carry + sm[t] - v;  // exclusive
        carry += sm[255];
        __syncthreads();
    }
    if (t == 0) tot[b] = carry;
}

// Pass C: re-read chunk edges, rank via LDS cursors (bbase from tot-scan +
// off), write packed (s | (d&mask)<<17) into exclusive slab ranges.
__global__ __launch_bounds__(256) void k_place(
    const int* __restrict__ ei, int E, int N, int shift,
    const int* __restrict__ off, const int* __restrict__ tot,
    unsigned* __restrict__ bslab)
{
    __shared__ int cur[NBK];
    __shared__ int ps[256];
    int c = blockIdx.x;
    int t = threadIdx.x;
    int carry = 0;
    for (int b0 = 0; b0 < NBK; b0 += 256) {
        int v = tot[b0 + t];
        ps[t] = v;
        __syncthreads();
        for (int o = 1; o < 256; o <<= 1) {
            int u = (t >= o) ? ps[t - o] : 0;
            __syncthreads();
            ps[t] += u;
            __syncthreads();
        }
        cur[b0 + t] = carry + ps[t] - v + off[(size_t)c * NBK + b0 + t];
        carry += ps[255];
        __syncthreads();
    }
    __syncthreads();

    int Etot = E + N;
    int base = c * CH;
    int lim = min(base + CH, Etot);
    int mask = (1 << shift) - 1;
    for (int e = base + t; e < lim; e += 256) {
        int s, d;
        if (e < E) { s = ei[e]; d = ei[E + e]; }
        else       { s = e - E; d = s; }
        int b = d >> shift;
        int pos = atomicAdd(&cur[b], 1);  // LDS atomic
        bslab[pos] = (unsigned)s | ((unsigned)(d & mask) << 17);
    }
}

// Pass D: block per bucket: LDS fine histogram + scan -> row_ptr, then place
// srcs into the bucket's csr_src window (L2-local). LDS atomics only.
__global__ __launch_bounds__(256) void k_csr2(
    const int* __restrict__ tot, const unsigned* __restrict__ bslab,
    int shift, int* __restrict__ row_ptr, int* __restrict__ csr_src,
    int N, int Etot)
{
    __shared__ int sdeg[1024];
    __shared__ int scur[1024];
    __shared__ int ps[256];
    __shared__ int bb[NBK + 1];
    int b = blockIdx.x;
    int tid = threadIdx.x;

    // bbase from tot: 2-batch exclusive scan (coalesced, cheap)
    int carry = 0;
    for (int b0 = 0; b0 < NBK; b0 += 256) {
        int v = tot[b0 + tid];
        ps[tid] = v;
        __syncthreads();
        for (int o = 1; o < 256; o <<= 1) {
            int u = (tid >= o) ? ps[tid - o] : 0;
            __syncthreads();
            ps[tid] += u;
            __syncthreads();
        }
        bb[b0 + tid] = carry + ps[tid] - v;
        carry += ps[255];
        __syncthreads();
    }
    if (tid == 0) bb[NBK] = carry;
    __syncthreads();

    int beg = bb[b], end = bb[b + 1];
    int nodes = 1 << shift;            // 256 (shift=8); LDS sized for <=1024
    int node0 = b << shift;
    for (int i = tid; i < nodes; i += 256) sdeg[i] = 0;
    __syncthreads();
    for (int i = beg + tid; i < end; i += 256)
        atomicAdd(&sdeg[bslab[i] >> 17], 1);
    __syncthreads();
    int per = (nodes + 255) / 256;
    int mybase = tid * per;
    int sum = 0;
    for (int j = 0; j < per; j++) sum += sdeg[mybase + j];
    ps[tid] = sum;
    __syncthreads();
    int v0 = ps[tid];
    for (int o = 1; o < 256; o <<= 1) {
        int v = (tid >= o) ? ps[tid - o] : 0;
        __syncthreads();
        ps[tid] += v;
        __syncthreads();
    }
    int run = ps[tid] - v0;
    for (int j = 0; j < per; j++) {
        int i = mybase + j;
        int dgi = sdeg[i];
        scur[i] = beg + run;
        int node = node0 + i;
        if (node < N) row_ptr[node] = beg + run;
        run += dgi;
    }
    if (b == 0 && tid == 0) row_ptr[N] = Etot;
    __syncthreads();
    for (int i = beg + tid; i < end; i += 256) {
        unsigned w = bslab[i];
        int pos = atomicAdd(&scur[w >> 17], 1);  // LDS atomic
        csr_src[pos] = (int)(w & 0x1FFFFu);
    }
}

// ===========================================================================
// xl1 = x @ W1 [N,64] -> packed bf16; as1/ad1 logits (pre-scaled by log2e).
// REGISTER-BLOCKED: each thread computes 4 NODES x 16 CHANNELS (64 acc) —
// each LDS w-read feeds 4 FMAs. Block covers 256 nodes. First NCHv blocks
// also run the CSR pass-A chunk histogram.
// ===========================================================================
__device__ __forceinline__ void emit_node1(
    const float* acc, int n, int q, int c0,
    const float* asrc, const float* adst,
    unsigned* __restrict__ xl1b, float* __restrict__ as1,
    float* __restrict__ ad1)
{
    uint4 pk0, pk1;
    pk0.x = pack_bf16(acc[0], acc[1]);  pk0.y = pack_bf16(acc[2], acc[3]);
    pk0.z = pack_bf16(acc[4], acc[5]);  pk0.w = pack_bf16(acc[6], acc[7]);
    pk1.x = pack_bf16(acc[8], acc[9]);  pk1.y = pack_bf16(acc[10], acc[11]);
    pk1.z = pack_bf16(acc[12], acc[13]); pk1.w = pack_bf16(acc[14], acc[15]);
    uint4* xo = (uint4*)(xl1b + (size_t)n * 32 + q * 8);
    xo[0] = pk0;
    xo[1] = pk1;
#pragma unroll
    for (int hh = 0; hh < 2; hh++) {
        float s = 0.0f, t = 0.0f;
#pragma unroll
        for (int c = 0; c < 8; c++) {
            s = fmaf(acc[hh * 8 + c], asrc[c0 + hh * 8 + c], s);
            t = fmaf(acc[hh * 8 + c], adst[c0 + hh * 8 + c], t);
        }
        as1[(size_t)n * 8 + 2 * q + hh] = s * LOG2E;
        ad1[(size_t)n * 8 + 2 * q + hh] = t * LOG2E;
    }
}

__global__ __launch_bounds__(256) void k_gemm1(
    const float* __restrict__ x, const float* __restrict__ W1,
    const float* __restrict__ a_src1, const float* __restrict__ a_dst1,
    unsigned* __restrict__ xl1b, float* __restrict__ as1,
    float* __restrict__ ad1, int N, int F,
    const int* __restrict__ ei, int E, int shift, int NCHv,
    int* __restrict__ cnt)
{
    __shared__ float Ws[128 * 64];
    __shared__ float asrc[64];
    __shared__ float adst[64];
    __shared__ int hist[NBK];

    // ---- fused CSR pass A (chunk histogram) ----
    if (blockIdx.x < NCHv) {
        for (int i = threadIdx.x; i < NBK; i += 256) hist[i] = 0;
        __syncthreads();
        int Etot = E + N;
        int base = blockIdx.x * CH;
        int lim = min(base + CH, Etot);
        for (int e = base + threadIdx.x; e < lim; e += 256) {
            int d = (e < E) ? ei[E + e] : (e - E);
            atomicAdd(&hist[d >> shift], 1);
        }
        __syncthreads();
        for (int i = threadIdx.x; i < NBK; i += 256)
            cnt[(size_t)blockIdx.x * NBK + i] = hist[i];
    }
    if (blockIdx.x * 256 >= N) return;   // hist-only block

    // ---- GEMM part ----
    for (int i = threadIdx.x; i < F * 64; i += 256) Ws[i] = W1[i];
    if (threadIdx.x < 64) {
        asrc[threadIdx.x] = a_src1[threadIdx.x];
        adst[threadIdx.x] = a_dst1[threadIdx.x];
    }
    __syncthreads();

    int q = threadIdx.x & 3;              // channel quarter: 16q..16q+15
    int n0 = blockIdx.x * 256 + (threadIdx.x >> 2) * 4;  // 4 consecutive nodes
    if (n0 >= N) return;
    int c0 = q * 16;
    int n1 = min(n0 + 1, N - 1);
    int n2 = min(n0 + 2, N - 1);
    int n3 = min(n0 + 3, N - 1);

    float acc0[16], acc1[16], acc2[16], acc3[16];
#pragma unroll
    for (int c = 0; c < 16; c++) { acc0[c]=0.f; acc1[c]=0.f; acc2[c]=0.f; acc3[c]=0.f; }

    const float4* xr0 = (const float4*)(x + (size_t)n0 * F);
    const float4* xr1 = (const float4*)(x + (size_t)n1 * F);
    const float4* xr2 = (const float4*)(x + (size_t)n2 * F);
    const float4* xr3 = (const float4*)(x + (size_t)n3 * F);

#define GEMM1_ROW(comp, ridx)                                        \
    { const float* w = &Ws[(k4 * 4 + ridx) * 64 + c0];               \
      _Pragma("unroll")                                              \
      for (int c = 0; c < 16; c++) {                                 \
          float wc = w[c];                                           \
          acc0[c] = fmaf(xv0.comp, wc, acc0[c]);                     \
          acc1[c] = fmaf(xv1.comp, wc, acc1[c]);                     \
          acc2[c] = fmaf(xv2.comp, wc, acc2[c]);                     \
          acc3[c] = fmaf(xv3.comp, wc, acc3[c]); } }

    for (int k4 = 0; k4 < F / 4; k4++) {
        float4 xv0 = xr0[k4];
        float4 xv1 = xr1[k4];
        float4 xv2 = xr2[k4];
        float4 xv3 = xr3[k4];
        GEMM1_ROW(x, 0)
        GEMM1_ROW(y, 1)
        GEMM1_ROW(z, 2)
        GEMM1_ROW(w, 3)
    }
#undef GEMM1_ROW

    emit_node1(acc0, n0, q, c0, asrc, adst, xl1b, as1, ad1);
    if (n0 + 1 < N) emit_node1(acc1, n0 + 1, q, c0, asrc, adst, xl1b, as1, ad1);
    if (n0 + 2 < N) emit_node1(acc2, n0 + 2, q, c0, asrc, adst, xl1b, as1, ad1);
    if (n0 + 3 < N) emit_node1(acc3, n0 + 3, q, c0, asrc, adst, xl1b, as1, ad1);
}

// ===========================================================================
// Layer-1 aggregation (pull): TWO DST NODES PER WAVE (32 lanes each:
// 4 edge groups x 8 channel lanes). THIS ROUND: edge loop unrolled x4
// (edges i, i+4, i+8, i+12; 12 loads in flight per dst vs 6) to test the
// MLP-limited vs MSHR-limited hypothesis for the 3.57 TB/s gather plateau.
// ===========================================================================
__device__ __forceinline__ void agg1_edge(
    float e, const uint4& k, float* ax)
{
    ax[0] = fmaf(e, bf_lo(k.x), ax[0]);
    ax[1] = fmaf(e, bf_hi(k.x), ax[1]);
    ax[2] = fmaf(e, bf_lo(k.y), ax[2]);
    ax[3] = fmaf(e, bf_hi(k.y), ax[3]);
    ax[4] = fmaf(e, bf_lo(k.z), ax[4]);
    ax[5] = fmaf(e, bf_hi(k.z), ax[5]);
    ax[6] = fmaf(e, bf_lo(k.w), ax[6]);
    ax[7] = fmaf(e, bf_hi(k.w), ax[7]);
}

__global__ __launch_bounds__(256) void k_agg1(
    const int* __restrict__ row_ptr, const int* __restrict__ csr_src,
    const float* __restrict__ as1, const float* __restrict__ ad1,
    const unsigned* __restrict__ xl1b, const float* __restrict__ b1,
    float* __restrict__ h1, int N)
{
    int d = blockIdx.x * 8 + ((threadIdx.x >> 6) << 1) + ((threadIdx.x >> 5) & 1);
    if (d >= N) return;
    int lane = threadIdx.x & 31;   // lane within this dst's half-wave
    int g = lane >> 3;   // edge group 0..3
    int l = lane & 7;    // head / channel octet

    int beg = row_ptr[d], end = row_ptr[d + 1];
    float adh = ad1[(size_t)d * 8 + l];

    float ax[8];
#pragma unroll
    for (int j = 0; j < 8; j++) ax[j] = 0.f;
    float den = 0.f;

    int i = beg + g;
    for (; i + 12 < end; i += 16) {
        int s0 = csr_src[i];
        int s1 = csr_src[i + 4];
        int s2 = csr_src[i + 8];
        int s3 = csr_src[i + 12];
        size_t q0 = (size_t)s0 * 8 + l;
        size_t q1 = (size_t)s1 * 8 + l;
        size_t q2 = (size_t)s2 * 8 + l;
        size_t q3 = (size_t)s3 * 8 + l;
        float al0 = as1[q0] + adh;
        float al1 = as1[q1] + adh;
        float al2 = as1[q2] + adh;
        float al3 = as1[q3] + adh;
        uint4 k0 = *(const uint4*)(xl1b + (q0 << 2));
        uint4 k1 = *(const uint4*)(xl1b + (q1 << 2));
        uint4 k2 = *(const uint4*)(xl1b + (q2 << 2));
        uint4 k3 = *(const uint4*)(xl1b + (q3 << 2));
        al0 = fmaxf(al0, NEG_SLOPE * al0);
        al1 = fmaxf(al1, NEG_SLOPE * al1);
        al2 = fmaxf(al2, NEG_SLOPE * al2);
        al3 = fmaxf(al3, NEG_SLOPE * al3);
        float e0 = __builtin_amdgcn_exp2f(al0);
        float e1 = __builtin_amdgcn_exp2f(al1);
        float e2 = __builtin_amdgcn_exp2f(al2);
        float e3 = __builtin_amdgcn_exp2f(al3);
        agg1_edge(e0, k0, ax);
        agg1_edge(e1, k1, ax);
        agg1_edge(e2, k2, ax);
        agg1_edge(e3, k3, ax);
        den += (e0 + e1) + (e2 + e3);
    }
    for (; i < end; i += 4) {      // 0..3 leftover edges for this group
        int s0 = csr_src[i];
        size_t q0 = (size_t)s0 * 8 + l;
        float al0 = as1[q0] + adh;
        uint4 k0 = *(const uint4*)(xl1b + (q0 << 2));
        al0 = fmaxf(al0, NEG_SLOPE * al0);
        float e0 = __builtin_amdgcn_exp2f(al0);
        agg1_edge(e0, k0, ax);
        den += e0;
    }

    // Reduce over the 4 edge groups: masks 8,16 stay inside each 32-lane half.
#pragma unroll
    for (int m = 8; m < 32; m <<= 1) {
#pragma unroll
        for (int j = 0; j < 8; j++) ax[j] += __shfl_xor(ax[j], m);
        den += __shfl_xor(den, m);
    }

    if (g == 0) {
        float inv = __builtin_amdgcn_rcpf(den + GAT_EPS);
        const float4* bb = (const float4*)(b1 + l * 8);
        float4 b0 = bb[0], b1v = bb[1];
        float4 o0, o1;
        float v;
        v = fmaf(ax[0], inv, b0.x);  o0.x = v > 0.f ? v : __expf(v) - 1.f;
        v = fmaf(ax[1], inv, b0.y);  o0.y = v > 0.f ? v : __expf(v) - 1.f;
        v = fmaf(ax[2], inv, b0.z);  o0.z = v > 0.f ? v : __expf(v) - 1.f;
        v = fmaf(ax[3], inv, b0.w);  o0.w = v > 0.f ? v : __expf(v) - 1.f;
        v = fmaf(ax[4], inv, b1v.x); o1.x = v > 0.f ? v : __expf(v) - 1.f;
        v = fmaf(ax[5], inv, b1v.y); o1.y = v > 0.f ? v : __expf(v) - 1.f;
        v = fmaf(ax[6], inv, b1v.z); o1.z = v > 0.f ? v : __expf(v) - 1.f;
        v = fmaf(ax[7], inv, b1v.w); o1.w = v > 0.f ? v : __expf(v) - 1.f;
        float4* op = (float4*)(h1 + (size_t)d * 64 + l * 8);
        op[0] = o0;
        op[1] = o1;
    }
}

// ===========================================================================
// Layer-2 node transform: REGISTER-BLOCKED — each thread computes 2 NODES x
// 20 CHANNELS (40 acc); each LDS w-read feeds 2 FMAs. Block covers 256
// nodes. Rows stride 24 uints (96 B): 20 payload + embedded as2 at uint 20.
// ===========================================================================
__global__ __launch_bounds__(256) void k_node2(
    const float* __restrict__ h1, const float* __restrict__ W2,
    const float* __restrict__ a_src2, const float* __restrict__ a_dst2,
    unsigned* __restrict__ xl2b, float* __restrict__ ad2, int N)
{
    __shared__ float Ws[64 * 40];
    __shared__ float a2s[40];
    __shared__ float a2d[40];
    for (int i = threadIdx.x; i < 64 * 40; i += 256) Ws[i] = W2[i];
    if (threadIdx.x < 40) {
        a2s[threadIdx.x] = a_src2[threadIdx.x];
        a2d[threadIdx.x] = a_dst2[threadIdx.x];
    }
    __syncthreads();

    int q = threadIdx.x & 1;              // channel half: 20q..20q+19
    int n0 = blockIdx.x * 256 + (threadIdx.x >> 1) * 2;  // 2 consecutive nodes
    if (n0 >= N) return;
    int c0 = q * 20;
    int n1 = min(n0 + 1, N - 1);

    float o0[20], o1[20];
#pragma unroll
    for (int j = 0; j < 20; j++) { o0[j] = 0.f; o1[j] = 0.f; }

    const float4* hr0 = (const float4*)(h1 + (size_t)n0 * 64);
    const float4* hr1 = (const float4*)(h1 + (size_t)n1 * 64);

#define NODE2_ROW(comp, ridx)                                        \
    { const float* w = &Ws[(k4 * 4 + ridx) * 40 + c0];               \
      _Pragma("unroll")                                              \
      for (int j = 0; j < 20; j++) {                                 \
          float wj = w[j];                                           \
          o0[j] = fmaf(ha.comp, wj, o0[j]);                          \
          o1[j] = fmaf(hb.comp, wj, o1[j]); } }

    for (int k4 = 0; k4 < 16; k4++) {
        float4 ha = hr0[k4];
        float4 hb = hr1[k4];
        NODE2_ROW(x, 0)
        NODE2_ROW(y, 1)
        NODE2_ROW(z, 2)
        NODE2_ROW(w, 3)
    }
#undef NODE2_ROW

    float s0 = 0.f, t0 = 0.f, s1 = 0.f, t1 = 0.f;
#pragma unroll
    for (int j = 0; j < 20; j++) {
        s0 = fmaf(o0[j], a2s[c0 + j], s0);
        t0 = fmaf(o0[j], a2d[c0 + j], t0);
        s1 = fmaf(o1[j], a2s[c0 + j], s1);
        t1 = fmaf(o1[j], a2d[c0 + j], t1);
    }
    s0 += __shfl_xor(s0, 1);
    t0 += __shfl_xor(t0, 1);
    s1 += __shfl_xor(s1, 1);
    t1 += __shfl_xor(t1, 1);
    if (q == 0) {
        xl2b[(size_t)n0 * 24 + 20] = __float_as_uint(s0 * LOG2E);
        ad2[n0] = t0 * LOG2E;
        if (n0 + 1 < N) {
            xl2b[(size_t)(n0 + 1) * 24 + 20] = __float_as_uint(s1 * LOG2E);
            ad2[n0 + 1] = t1 * LOG2E;
        }
    }

    unsigned* xo0 = xl2b + (size_t)n0 * 24 + q * 10;
#pragma unroll
    for (int p = 0; p < 10; p++) xo0[p] = pack_bf16(o0[2 * p], o0[2 * p + 1]);
    if (n0 + 1 < N) {
        unsigned* xo1 = xl2b + (size_t)(n0 + 1) * 24 + q * 10;
#pragma unroll
        for (int p = 0; p < 10; p++) xo1[p] = pack_bf16(o1[2 * p], o1[2 * p + 1]);
    }
}

// ===========================================================================
// Layer-2 aggregation (pull): TWO DST NODES PER WAVE, 4-deep edge unroll
// (same MLP experiment as agg1). Rows stride 24: lane l<5 loads uint4 at
// +4l; the as2 logit is row[20]. Lanes l>=5 fully predicated off.
// ===========================================================================
__global__ __launch_bounds__(256) void k_agg2(
    const int* __restrict__ row_ptr, const int* __restrict__ csr_src,
    const float* __restrict__ ad2,
    const unsigned* __restrict__ xl2b, const float* __restrict__ b2,
    float* __restrict__ out, int N)
{
    int d = blockIdx.x * 8 + ((threadIdx.x >> 6) << 1) + ((threadIdx.x >> 5) & 1);
    if (d >= N) return;
    int lane = threadIdx.x & 31;
    int g = lane >> 3;   // edge group 0..3
    int l = lane & 7;
    if (l >= 5) return;  // only 5 octets of 40 channels; reduction is l-local

    int beg = row_ptr[d], end = row_ptr[d + 1];
    float add = ad2[d];

    float ax[8];
#pragma unroll
    for (int j = 0; j < 8; j++) ax[j] = 0.f;
    float den = 0.f;

    int i = beg + g;
    for (; i + 12 < end; i += 16) {
        int s0 = csr_src[i];
        int s1 = csr_src[i + 4];
        int s2 = csr_src[i + 8];
        int s3 = csr_src[i + 12];
        const unsigned* r0 = xl2b + (size_t)s0 * 24;
        const unsigned* r1 = xl2b + (size_t)s1 * 24;
        const unsigned* r2 = xl2b + (size_t)s2 * 24;
        const unsigned* r3 = xl2b + (size_t)s3 * 24;
        float al0 = __uint_as_float(r0[20]) + add;
        float al1 = __uint_as_float(r1[20]) + add;
        float al2 = __uint_as_float(r2[20]) + add;
        float al3 = __uint_as_float(r3[20]) + add;
        uint4 k0 = *(const uint4*)(r0 + l * 4);
        uint4 k1 = *(const uint4*)(r1 + l * 4);
        uint4 k2 = *(const uint4*)(r2 + l * 4);
        uint4 k3 = *(const uint4*)(r3 + l * 4);
        al0 = fmaxf(al0, NEG_SLOPE * al0);
        al1 = fmaxf(al1, NEG_SLOPE * al1);
        al2 = fmaxf(al2, NEG_SLOPE * al2);
        al3 = fmaxf(al3, NEG_SLOPE * al3);
        float e0 = __builtin_amdgcn_exp2f(al0);
        float e1 = __builtin_amdgcn_exp2f(al1);
        float e2 = __builtin_amdgcn_exp2f(al2);
        float e3 = __builtin_amdgcn_exp2f(al3);
        agg1_edge(e0, k0, ax);
        agg1_edge(e1, k1, ax);
        agg1_edge(e2, k2, ax);
        agg1_edge(e3, k3, ax);
        den += (e0 + e1) + (e2 + e3);
    }
    for (; i < end; i += 4) {      // 0..3 leftover edges for this group
        int s0 = csr_src[i];
        const unsigned* r0 = xl2b + (size_t)s0 * 24;
        float al0 = __uint_as_float(r0[20]) + add;
        uint4 k0 = *(const uint4*)(r0 + l * 4);
        al0 = fmaxf(al0, NEG_SLOPE * al0);
        float e0 = __builtin_amdgcn_exp2f(al0);
        agg1_edge(e0, k0, ax);
        den += e0;
    }

#pragma unroll
    for (int m = 8; m < 32; m <<= 1) {
#pragma unroll
        for (int j = 0; j < 8; j++) ax[j] += __shfl_xor(ax[j], m);
        den += __shfl_xor(den, m);
    }

    if (g == 0) {
        float inv = __builtin_amdgcn_rcpf(den + GAT_EPS);
        float* op = out + (size_t)d * 40 + l * 8;
        const float* bb = b2 + l * 8;
#pragma unroll
        for (int j = 0; j < 8; j++) op[j] = fmaf(ax[j], inv, bb[j]);
    }
}

extern "C" void kernel_launch(void* const* d_in, const int* in_sizes, int n_in,
                              void* d_out, int out_size, void* d_ws, size_t ws_size,
                              hipStream_t stream) {
    const float* x      = (const float*)d_in[0];
    const int*   ei     = (const int*)d_in[1];     // int32 on device
    const float* W1     = (const float*)d_in[2];
    const float* a_src1 = (const float*)d_in[3];
    const float* a_dst1 = (const float*)d_in[4];
    const float* b1     = (const float*)d_in[5];
    const float* W2     = (const float*)d_in[6];
    const float* a_src2 = (const float*)d_in[7];
    const float* a_dst2 = (const float*)d_in[8];
    const float* b2     = (const float*)d_in[9];

    int F = in_sizes[2] / 64;      // 128
    int N = in_sizes[0] / F;       // 100000
    int E = in_sizes[1] / 2;       // 1600000
    int Etot = E + N;
    int NCHv = (Etot + CH - 1) / CH;  // 831 chunks
    int shift = 8;                    // 256 nodes/bucket; 391 buckets used
    while (((N - 1) >> shift) >= NBK) shift++;  // safety (LDS supports shift<=10)

    // Workspace (4-byte words).
    unsigned* xl1b    = (unsigned*)d_ws;                   // N*32
    float*    h1      = (float*)(xl1b + (size_t)N * 32);   // N*64
    float*    as1     = h1 + (size_t)N * 64;               // N*8
    float*    ad1     = as1 + (size_t)N * 8;               // N*8
    int*      row_ptr = (int*)(ad1 + (size_t)N * 8);       // N+1
    int*      csr_src = row_ptr + (N + 1);                 // Etot
    unsigned* bslab   = (unsigned*)(csr_src + Etot);       // Etot
    // CSR-build scratch ALIASED onto h1 (h1 first written by k_agg1, after
    // the CSR build completes; N*64 floats >= 2*NCHv*NBK + NBK ints):
    int*      cnt     = (int*)h1;                          // NCHv*NBK
    int*      off     = cnt + (size_t)NCHv * NBK;          // NCHv*NBK
    int*      tot     = off + (size_t)NCHv * NBK;          // NBK
    // Layer-2 aliases (live only after k_agg1; originals dead by then):
    unsigned* xl2b    = xl1b;                              // N*24 rows (96 B)
    float*    ad2     = ad1;                               // N

    // ---- Layer-1 GEMM (256 nodes/block) + fused CSR pass A ----
    int gridG1 = (N + 255) / 256;
    if (gridG1 < NCHv) gridG1 = NCHv;
    k_gemm1<<<gridG1, 256, 0, stream>>>(x, W1, a_src1, a_dst1,
                                        xl1b, as1, ad1, N, F,
                                        ei, E, shift, NCHv, cnt);

    // ---- CSR build: deterministic counting sort, zero global atomics ----
    k_off_a<<<NBK, 256, 0, stream>>>(cnt, off, tot, NCHv);
    k_place<<<NCHv, 256, 0, stream>>>(ei, E, N, shift, off, tot, bslab);
    k_csr2 <<<NBK, 256, 0, stream>>>(tot, bslab, shift,
                                     row_ptr, csr_src, N, Etot);

    // ---- Layer 1 aggregation ----
    k_agg1 <<<(N + 7) / 8, 256, 0, stream>>>(row_ptr, csr_src, as1, ad1,
                                             xl1b, b1, h1, N);

    // ---- Layer 2 ----
    k_node2<<<(N + 255) / 256, 256, 0, stream>>>(h1, W2, a_src2, a_dst2,
                                                 xl2b, ad2, N);
    k_agg2 <<<(N + 7) / 8, 256, 0, stream>>>(row_ptr, csr_src, ad2,
                                             xl2b, b2, (float*)d_out, N);
}